// Round 5
// baseline (83.396 us; speedup 1.0000x reference)
//
#include <hip/hip_runtime.h>

#define HH 768
#define WW 768
#define BC 4
#define NPIX (BC * HH * WW)

typedef float f4 __attribute__((ext_vector_type(4)));
typedef float f2 __attribute__((ext_vector_type(2)));

// 8 outputs/thread: 4 cols (float4-aligned) x 2 rows (best ILP/TLP point, R2).
// Block (64,8): 256 cols x 16 rows -> map window 20 rows = 1.25x overfetch (R4's win).
// 576 blocks x 8 waves = 4608 waves = 4.5 waves/SIMD (R2's TLP).
__global__ __launch_bounds__(512) void conv_thresh_kernel(
    const float* __restrict__ bev_map,
    const float* __restrict__ bev_scale,
    float* __restrict__ out)  // out[0:N]=conv, out[N:2N]=mask
{
    const int tx = threadIdx.x;                      // 0..63
    const int ty = threadIdx.y;                      // 0..7
    const int x0 = (blockIdx.x * 64 + tx) * 4;       // output col base, multiple of 4
    const int y0 = blockIdx.y * 16 + ty * 2;         // output row base, 2 rows/thread
    const int b  = blockIdx.z;

    const size_t plane = (size_t)b * (HH * WW);
    const float* __restrict__ m = bev_map + plane;

    const bool leftok  = (x0 != 0);
    const bool rightok = (x0 != WW - 4);

    // Horizontal partial sums per row r (rows y0-2 .. y0+3) and output col j:
    //   h0 = w[x], h1 = w[x-1]+w[x+1], h2 = w[x-2]+w[x+2]   (w = relu(map))
    float h0[6][4], h1[6][4], h2[6][4];

#pragma unroll
    for (int r = 0; r < 6; ++r) {
        const int yy = y0 - 2 + r;
        const bool yok = (unsigned)yy < (unsigned)HH;   // uniform within wave (ty fixed)
        const float* rowp = m + yy * WW + x0;
        float w[8];                                     // w[i] = relu(map[yy][x0-2+i])
        if (yok) {
            f4 t = *(const f4*)rowp;
            w[2] = fmaxf(t.x, 0.f); w[3] = fmaxf(t.y, 0.f);
            w[4] = fmaxf(t.z, 0.f); w[5] = fmaxf(t.w, 0.f);
            if (leftok) {
                f2 t2 = *(const f2*)(rowp - 2);
                w[0] = fmaxf(t2.x, 0.f); w[1] = fmaxf(t2.y, 0.f);
            } else { w[0] = 0.f; w[1] = 0.f; }
            if (rightok) {
                f2 t2 = *(const f2*)(rowp + 4);
                w[6] = fmaxf(t2.x, 0.f); w[7] = fmaxf(t2.y, 0.f);
            } else { w[6] = 0.f; w[7] = 0.f; }
        } else {
#pragma unroll
            for (int i = 0; i < 8; ++i) w[i] = 0.f;
        }
#pragma unroll
        for (int j = 0; j < 4; ++j) {
            h0[r][j] = w[j + 2];
            h1[r][j] = w[j + 1] + w[j + 3];
            h2[r][j] = w[j]     + w[j + 4];
        }
    }

#pragma unroll
    for (int k = 0; k < 2; ++k) {
        const int oy = y0 + k;
        const size_t idx = plane + (size_t)oy * WW + x0;
        const f4 scv = __builtin_nontemporal_load((const f4*)(bev_scale + idx));
        f4 conv, mask;
#pragma unroll
        for (int j = 0; j < 4; ++j) {
            // Ring sums by r^2 from horizontal partials (window rows k..k+4)
            const float c0 = h0[k + 2][j];
            const float s1 = h1[k + 2][j] + h0[k + 1][j] + h0[k + 3][j];
            const float s2 = h1[k + 1][j] + h1[k + 3][j];
            const float s4 = h2[k + 2][j] + h0[k][j]     + h0[k + 4][j];
            const float s5 = h2[k + 1][j] + h2[k + 3][j] + h1[k][j] + h1[k + 4][j];
            const float s8 = h2[k][j]     + h2[k + 4][j];

            const float sc = scv[j];
            const float t1 = -1.0f / (2.0f * sc * sc + 1e-6f);
            const float e1 = __expf(t1);      // w(r2) = e1^r2
            const float e2 = e1 * e1;
            const float e4 = e2 * e2;
            const float e5 = e4 * e1;
            const float e8 = e4 * e4;

            float cv = c0;
            cv = fmaf(e1, s1, cv);
            cv = fmaf(e2, s2, cv);
            cv = fmaf(e4, s4, cv);
            cv = fmaf(e5, s5, cv);
            cv = fmaf(e8, s8, cv);
            conv[j] = cv;
            mask[j] = (cv >= 0.5f) ? 1.0f : 0.0f;
        }
        __builtin_nontemporal_store(conv, (f4*)(out + idx));
        __builtin_nontemporal_store(mask, (f4*)(out + idx + (size_t)NPIX));
    }
}

extern "C" void kernel_launch(void* const* d_in, const int* in_sizes, int n_in,
                              void* d_out, int out_size, void* d_ws, size_t ws_size,
                              hipStream_t stream) {
    const float* bev_map   = (const float*)d_in[0];
    const float* bev_scale = (const float*)d_in[1];
    float* out = (float*)d_out;

    dim3 block(64, 8, 1);
    dim3 grid(WW / 256, HH / 16, BC);   // (3, 48, 4) = 576 blocks, 8 waves each
    conv_thresh_kernel<<<grid, block, 0, stream>>>(bev_map, bev_scale, out);
}

// Round 6
// 76.432 us; speedup vs baseline: 1.0911x; 1.0911x over previous
//
#include <hip/hip_runtime.h>

#define HH 768
#define WW 768
#define BC 4
#define NPIX (BC * HH * WW)

typedef float f4 __attribute__((ext_vector_type(4)));
typedef float f2 __attribute__((ext_vector_type(2)));

// R2 config (best: 77.7us bench) + cross-lane shuffle for halo columns.
// 8 outputs/thread: 4 cols (float4-aligned) x 2 rows. Block (64,4): 256x8 tile.
// Per row each lane loads ONE f4; halo cols come from neighbor lanes via
// __shfl_up/__shfl_down (wave=64 lanes = one ty row). Only lanes 0/63 load
// the 8B block-boundary halo. VMEM/thread: 6 map + ~0.2 halo + 2 scale + 4 st.
__global__ __launch_bounds__(256) void conv_thresh_kernel(
    const float* __restrict__ bev_map,
    const float* __restrict__ bev_scale,
    float* __restrict__ out)  // out[0:N]=conv, out[N:2N]=mask
{
    const int tx = threadIdx.x;                      // 0..63 == lane id
    const int ty = threadIdx.y;                      // 0..3
    const int x0 = (blockIdx.x * 64 + tx) * 4;       // output col base, multiple of 4
    const int y0 = blockIdx.y * 8 + ty * 2;          // output row base, 2 rows/thread
    const int b  = blockIdx.z;

    const size_t plane = (size_t)b * (HH * WW);
    const float* __restrict__ m = bev_map + plane;

    // Horizontal partial sums per row r (rows y0-2 .. y0+3) and output col j:
    //   h0 = w[x], h1 = w[x-1]+w[x+1], h2 = w[x-2]+w[x+2]   (w = relu(map))
    float h0[6][4], h1[6][4], h2[6][4];

#pragma unroll
    for (int r = 0; r < 6; ++r) {
        const int yy = y0 - 2 + r;
        const bool yok = (unsigned)yy < (unsigned)HH;   // uniform within wave (ty fixed)
        const float* rowp = m + yy * WW + x0;
        f4 t;
        if (yok) {
            t = *(const f4*)rowp;
            t.x = fmaxf(t.x, 0.f); t.y = fmaxf(t.y, 0.f);
            t.z = fmaxf(t.z, 0.f); t.w = fmaxf(t.w, 0.f);
        } else {
            t.x = 0.f; t.y = 0.f; t.z = 0.f; t.w = 0.f;
        }
        // halo from neighbor lanes (relu already applied)
        float lz = __shfl_up(t.z, 1);    // w[x0-2]
        float lw = __shfl_up(t.w, 1);    // w[x0-1]
        float rx = __shfl_down(t.x, 1);  // w[x0+4]
        float ry = __shfl_down(t.y, 1);  // w[x0+5]
        if (tx == 0) {                   // wave edge: halo lives in another block
            lz = 0.f; lw = 0.f;
            if (yok && x0 != 0) {
                f2 t2 = *(const f2*)(rowp - 2);
                lz = fmaxf(t2.x, 0.f); lw = fmaxf(t2.y, 0.f);
            }
        }
        if (tx == 63) {
            rx = 0.f; ry = 0.f;
            if (yok && x0 != WW - 4) {
                f2 t2 = *(const f2*)(rowp + 4);
                rx = fmaxf(t2.x, 0.f); ry = fmaxf(t2.y, 0.f);
            }
        }
        const float w0 = lz, w1 = lw, w2 = t.x, w3 = t.y,
                    w4 = t.z, w5 = t.w, w6 = rx, w7 = ry;
        h0[r][0] = w2; h1[r][0] = w1 + w3; h2[r][0] = w0 + w4;
        h0[r][1] = w3; h1[r][1] = w2 + w4; h2[r][1] = w1 + w5;
        h0[r][2] = w4; h1[r][2] = w3 + w5; h2[r][2] = w2 + w6;
        h0[r][3] = w5; h1[r][3] = w4 + w6; h2[r][3] = w3 + w7;
    }

#pragma unroll
    for (int k = 0; k < 2; ++k) {
        const int oy = y0 + k;
        const size_t idx = plane + (size_t)oy * WW + x0;
        const f4 scv = *(const f4*)(bev_scale + idx);
        f4 conv, mask;
#pragma unroll
        for (int j = 0; j < 4; ++j) {
            // Ring sums by r^2 from horizontal partials (window rows k..k+4)
            const float c0 = h0[k + 2][j];
            const float s1 = h1[k + 2][j] + h0[k + 1][j] + h0[k + 3][j];
            const float s2 = h1[k + 1][j] + h1[k + 3][j];
            const float s4 = h2[k + 2][j] + h0[k][j]     + h0[k + 4][j];
            const float s5 = h2[k + 1][j] + h2[k + 3][j] + h1[k][j] + h1[k + 4][j];
            const float s8 = h2[k][j]     + h2[k + 4][j];

            const float sc = scv[j];
            const float t1 = -1.0f / (2.0f * sc * sc + 1e-6f);
            const float e1 = __expf(t1);      // w(r2) = e1^r2
            const float e2 = e1 * e1;
            const float e4 = e2 * e2;
            const float e5 = e4 * e1;
            const float e8 = e4 * e4;

            float cv = c0;
            cv = fmaf(e1, s1, cv);
            cv = fmaf(e2, s2, cv);
            cv = fmaf(e4, s4, cv);
            cv = fmaf(e5, s5, cv);
            cv = fmaf(e8, s8, cv);
            conv[j] = cv;
            mask[j] = (cv >= 0.5f) ? 1.0f : 0.0f;
        }
        *(f4*)(out + idx) = conv;
        *(f4*)(out + idx + (size_t)NPIX) = mask;
    }
}

extern "C" void kernel_launch(void* const* d_in, const int* in_sizes, int n_in,
                              void* d_out, int out_size, void* d_ws, size_t ws_size,
                              hipStream_t stream) {
    const float* bev_map   = (const float*)d_in[0];
    const float* bev_scale = (const float*)d_in[1];
    float* out = (float*)d_out;

    dim3 block(64, 4, 1);
    dim3 grid(WW / 256, HH / 8, BC);   // (3, 96, 4) = 1152 blocks, 4 waves each
    conv_thresh_kernel<<<grid, block, 0, stream>>>(bev_map, bev_scale, out);
}